// Round 1
// baseline (10161.626 us; speedup 1.0000x reference)
//
#include <hip/hip_runtime.h>
#include <stdint.h>

// Problem constants (B=32, C1=64, C2=16, C3=16, N=8)
#define EPSF    1e-10f
#define NCHAIN  2048        // B*C1
#define SEQ     256         // C2*C3
#define NMAT    (NCHAIN*SEQ)

// Fréchet means live here between the two kernels (512 KB, fully
// rewritten by fm_kernel on every call -> deterministic).
__device__ float g_fm[NCHAIN * 64];

__device__ __forceinline__ float bp(float v, int srcLane) {
    return __shfl(v, srcLane, 64);
}

// Parallel-ordered Jacobi eigendecomposition of an 8x8 symmetric matrix
// distributed one element per lane: lane (i,j) holds A_ij. On return the
// diagonal lanes of A hold eigenvalues and V holds eigenvectors (columns),
// i.e. M = V diag(w) V^T.
//
// Round-robin schedule: 7 rounds x 4 disjoint plane rotations = 1 sweep.
// Packed nibble table: entry x = partner(x) | (is_second(x) << 3).
__device__ __forceinline__ void eigh8(float &A, float &V,
                                      const int i, const int j,
                                      const int nsweep) {
    const int i8 = i << 3, j8 = j << 3;
    V = (i == j) ? 1.0f : 0.0f;
    static const uint32_t RR[7] = {
        0xABC56781u, 0xCD6718B2u, 0xE7128CD3u, 0x1238DEF4u,
        0x348EF925u, 0x58F9A346u, 0x89AB4567u
    };
    #pragma unroll 1
    for (int sw = 0; sw < nsweep; ++sw) {
        #pragma unroll
        for (int r = 0; r < 7; ++r) {
            const uint32_t tab = RR[r];
            const uint32_t ej = (tab >> (j << 2)) & 15u;
            const int  pj  = (int)(ej & 7u);
            const bool js2 = (ej & 8u) != 0u;
            const int  p   = js2 ? pj : j;
            const int  q   = js2 ? j  : pj;
            // rotation parameters for the pair containing column j
            const float app = bp(A, p * 9);
            const float aqq = bp(A, q * 9);
            const float apq = bp(A, (p << 3) + q);
            const bool  tiny = fabsf(apq) < 1e-30f;
            const float tau  = (aqq - app) / (tiny ? 1.0f : (2.0f * apq));
            float t = copysignf(1.0f, tau) /
                      (fabsf(tau) + sqrtf(fmaf(tau, tau, 1.0f)));
            t = tiny ? 0.0f : t;
            const float c = 1.0f / sqrtf(fmaf(t, t, 1.0f));
            const float s = t * c;
            const float alpj = c;
            const float betj = js2 ? s : -s;
            // row-pair parameters via transpose shuffle (alpha/beta depend
            // only on the index; lane (j,i) holds them for index i)
            const float alpi = bp(alpj, j8 + i);
            const float beti = bp(betj, j8 + i);
            const int   pi_  = (int)((tab >> (i << 2)) & 7u);
            // column update: A <- A J
            const float Ac = bp(A, i8 + pj);
            A = fmaf(betj, Ac, alpj * A);
            // row update: A <- J^T A
            const float Ar = bp(A, (pi_ << 3) + j);
            A = fmaf(beti, Ar, alpi * A);
            // eigenvector update: V <- V J
            const float Vc = bp(V, i8 + pj);
            V = fmaf(betj, Vc, alpj * V);
        }
    }
}

// ---------------- Phase 1: recursive Frechet mean (sequential scan) -------
__global__ void __launch_bounds__(256)
fm_kernel(const float* __restrict__ x) {
    const int wid  = (blockIdx.x << 2) + (threadIdx.x >> 6);   // chain id
    const int lane = threadIdx.x & 63;
    const int i = lane >> 3, j = lane & 7;
    const int i8 = i << 3, j8 = j << 3;

    const float* __restrict__ base = x + (size_t)wid * (SEQ * 64);
    float M = base[lane];                      // M_1 = X_1

    #pragma unroll 1
    for (int k = 1; k < SEQ; ++k) {
        const float Xk = base[(k << 6) + lane];
        const float wk = 1.0f / (float)(k + 1);

        // eigh(M)
        float A = M, V;
        eigh8(A, V, i, j, 6);
        const float evj = fmaxf(bp(A, j * 9), EPSF);
        const float swj = sqrtf(evj);
        const float rwj = 1.0f / swj;

        // Msq = V diag(sw) V^T ; Misq = V diag(1/sw) V^T  (fused)
        const float Ts = V * swj;
        const float Tr = V * rwj;
        float Msq = 0.0f, Misq = 0.0f;
        #pragma unroll
        for (int kk = 0; kk < 8; ++kk) {
            const float vjk = bp(V, j8 + kk);
            Msq  = fmaf(bp(Ts, i8 + kk), vjk, Msq);
            Misq = fmaf(bp(Tr, i8 + kk), vjk, Misq);
        }

        // S = Misq Xk Misq, symmetrized
        float t1 = 0.0f;
        #pragma unroll
        for (int kk = 0; kk < 8; ++kk)
            t1 = fmaf(bp(Misq, i8 + kk), bp(Xk, (kk << 3) + j), t1);
        float S = 0.0f;
        #pragma unroll
        for (int kk = 0; kk < 8; ++kk)
            S = fmaf(bp(t1, i8 + kk), bp(Misq, (kk << 3) + j), S);
        S = 0.5f * (S + bp(S, j8 + i));

        // spd_power(S, wk) = V2 diag(clip(w2)^wk) V2^T
        float V2;
        eigh8(S, V2, i, j, 6);
        const float ev2 = fmaxf(bp(S, j * 9), EPSF);
        const float pw  = exp2f(wk * log2f(ev2));
        const float Tp  = V2 * pw;
        float P = 0.0f;
        #pragma unroll
        for (int kk = 0; kk < 8; ++kk)
            P = fmaf(bp(Tp, i8 + kk), bp(V2, j8 + kk), P);

        // Mn = Msq P Msq, symmetrized
        float t4 = 0.0f;
        #pragma unroll
        for (int kk = 0; kk < 8; ++kk)
            t4 = fmaf(bp(Msq, i8 + kk), bp(P, (kk << 3) + j), t4);
        float Mn = 0.0f;
        #pragma unroll
        for (int kk = 0; kk < 8; ++kk)
            Mn = fmaf(bp(t4, i8 + kk), bp(Msq, (kk << 3) + j), Mn);
        M = 0.5f * (Mn + bp(Mn, j8 + i));
    }

    g_fm[(wid << 6) + lane] = M;
}

// ---------------- Phase 2: GL metric distances ----------------------------
__global__ void __launch_bounds__(256)
dist_kernel(const float* __restrict__ x, float* __restrict__ out) {
    const int wid  = (blockIdx.x << 2) + (threadIdx.x >> 6);   // matrix id
    const int lane = threadIdx.x & 63;
    const int i = lane >> 3, j = lane & 7;
    const int i8 = i << 3, j8 = j << 3;
    const int chain = wid >> 8;                                // / SEQ

    float Xw = x[(size_t)wid * 64 + lane];
    float Yv = g_fm[(chain << 6) + lane];

    // A = X^{-1} FM via pivot-free Gauss-Jordan (X SPD, well-conditioned)
    #pragma unroll
    for (int k = 0; k < 8; ++k) {
        const float piv = bp(Xw, k * 9);
        const float pr  = 1.0f / piv;
        const float xk  = bp(Xw, (k << 3) + j) * pr;
        const float yk  = bp(Yv, (k << 3) + j) * pr;
        const float xik = bp(Xw, i8 + k);
        const bool  isk = (i == k);
        const float m_  = isk ? 0.0f : xik;
        Xw = isk ? xk : fmaf(-m_, xk, Xw);
        Yv = isk ? yk : fmaf(-m_, yk, Yv);
    }
    const float Av = Yv;

    // B = A^T A
    float Bv = 0.0f;
    #pragma unroll
    for (int kk = 0; kk < 8; ++kk)
        Bv = fmaf(bp(Av, (kk << 3) + i), bp(Av, (kk << 3) + j), Bv);

    // eigh(B): sigma^2 = eigvals, V = right singular vectors
    float V;
    eigh8(Bv, V, i, j, 6);
    const float sig2 = fmaxf(bp(Bv, j * 9), 1e-20f);
    const float rsig = 1.0f / sqrtf(sig2);
    const float lsj  = 0.5f * logf(sig2);      // log(sigma_j), sigma >= 1e-10

    // U = A V Sigma^{-1}
    float AV = 0.0f;
    #pragma unroll
    for (int kk = 0; kk < 8; ++kk)
        AV = fmaf(bp(Av, i8 + kk), bp(V, (kk << 3) + j), AV);
    const float U = AV * rsig;

    // W = V^T U ; dist = sum_ij ls_i ls_j W_ij W_ji
    float W = 0.0f;
    #pragma unroll
    for (int kk = 0; kk < 8; ++kk)
        W = fmaf(bp(V, (kk << 3) + i), bp(U, (kk << 3) + j), W);
    const float Wt  = bp(W, j8 + i);
    const float lsi = bp(lsj, j8 + i);

    float contrib = lsi * lsj * W * Wt;
    #pragma unroll
    for (int off = 32; off; off >>= 1)
        contrib += __shfl_xor(contrib, off, 64);

    if (lane == 0) out[wid] = contrib;
}

extern "C" void kernel_launch(void* const* d_in, const int* in_sizes, int n_in,
                              void* d_out, int out_size, void* d_ws, size_t ws_size,
                              hipStream_t stream) {
    const float* x = (const float*)d_in[0];
    float* out = (float*)d_out;
    (void)in_sizes; (void)n_in; (void)d_ws; (void)ws_size; (void)out_size;

    // Phase 1: 2048 chains, 1 wave each, 4 waves/block
    hipLaunchKernelGGL(fm_kernel, dim3(NCHAIN / 4), dim3(256), 0, stream, x);
    // Phase 2: 524288 matrices, 1 wave each
    hipLaunchKernelGGL(dist_kernel, dim3(NMAT / 4), dim3(256), 0, stream, x, out);
}

// Round 2
// 4273.471 us; speedup vs baseline: 2.3778x; 2.3778x over previous
//
#include <hip/hip_runtime.h>
#include <stdint.h>

// Problem constants (B=32, C1=64, C2=16, C3=16, N=8)
#define EPSF    1e-10f
#define NCHAIN  2048        // B*C1
#define SEQ     256         // C2*C3
#define NMAT    (NCHAIN*SEQ)

// Fréchet means live here between the two kernels (512 KB, fully
// rewritten by fm_kernel on every call -> deterministic).
__device__ float g_fm[NCHAIN * 64];

__device__ __forceinline__ float bp(float v, int srcLane) {
    return __shfl(v, srcLane, 64);
}
__device__ __forceinline__ float rcpf(float x) { return __builtin_amdgcn_rcpf(x); }
__device__ __forceinline__ float rsqf(float x) { return __builtin_amdgcn_rsqf(x); }

// Parallel-ordered Jacobi eigendecomposition of an 8x8 symmetric matrix,
// one element per lane: lane (i,j) holds A_ij. On return diagonal lanes of
// A hold eigenvalues, V holds eigenvectors (columns): M = V diag(w) V^T.
// Round-robin schedule: 7 rounds x 4 disjoint plane rotations per sweep.
// Shuffle addresses are hoisted out of the sweep loop into statically
// indexed register arrays (rounds fully unrolled -> stays in VGPRs).
template<int NSWEEP>
__device__ __forceinline__ void eigh8(float &A, float &V,
                                      const int i, const int j) {
    const int i8 = i << 3, j8 = j << 3;
    const int a_tr = j8 + i;
    V = (i == j) ? 1.0f : 0.0f;
    static const uint32_t RR[7] = {
        0xABC56781u, 0xCD6718B2u, 0xE7128CD3u, 0x1238DEF4u,
        0x348EF925u, 0x58F9A346u, 0x89AB4567u
    };
    int a_pp[7], a_qq[7], a_pq[7], a_cl[7], a_rw[7];
    float sg[7];
    #pragma unroll
    for (int r = 0; r < 7; ++r) {
        const uint32_t tab = RR[r];
        const uint32_t ej = (tab >> (j << 2)) & 15u;
        const int  pj  = (int)(ej & 7u);
        const bool js2 = (ej & 8u) != 0u;
        const int  p   = js2 ? pj : j;
        const int  q   = js2 ? j  : pj;
        a_pp[r] = p * 9;
        a_qq[r] = q * 9;
        a_pq[r] = (p << 3) + q;
        a_cl[r] = i8 + pj;
        const int pi_ = (int)((tab >> (i << 2)) & 7u);
        a_rw[r] = (pi_ << 3) + j;
        sg[r] = js2 ? 1.0f : -1.0f;
    }
    #pragma unroll 1
    for (int sw = 0; sw < NSWEEP; ++sw) {
        #pragma unroll
        for (int r = 0; r < 7; ++r) {
            const float app = bp(A, a_pp[r]);
            const float aqq = bp(A, a_qq[r]);
            const float apq = bp(A, a_pq[r]);
            const bool  tiny = fabsf(apq) < 1e-30f;
            const float tau  = (aqq - app) * 0.5f * rcpf(apq);
            float t = copysignf(rcpf(fabsf(tau) + sqrtf(fmaf(tau, tau, 1.0f))), tau);
            t = tiny ? 0.0f : t;
            const float alpj = rsqf(fmaf(t, t, 1.0f));       // c
            const float betj = t * alpj * sg[r];             // +-s
            // row-pair params via transpose shuffle
            const float alpi = bp(alpj, a_tr);
            const float beti = bp(betj, a_tr);
            // column update: A <- A J
            const float Ac = bp(A, a_cl[r]);
            A = fmaf(betj, Ac, alpj * A);
            // row update: A <- J^T A
            const float Ar = bp(A, a_rw[r]);
            A = fmaf(beti, Ar, alpi * A);
            // eigenvector update: V <- V J
            const float Vc = bp(V, a_cl[r]);
            V = fmaf(betj, Vc, alpj * V);
        }
    }
}

// ---------------- Phase 1: recursive Frechet mean (sequential scan) -------
// Geodesic step via Cholesky (factor-invariance of the affine metric):
//   L = chol(M);  B = sym(L^{-1} X L^{-T});  M' = sym( (LV) diag(lam^w) (LV)^T )
// Exactly equals M^{1/2} (M^{-1/2} X M^{-1/2})^w M^{1/2} in exact arithmetic.
__global__ void __launch_bounds__(256)
fm_kernel(const float* __restrict__ x) {
    const int wid  = (blockIdx.x << 2) + (threadIdx.x >> 6);   // chain id
    const int lane = threadIdx.x & 63;
    const int i = lane >> 3, j = lane & 7;
    const int i8 = i << 3, j8 = j << 3;
    const int a_tr = j8 + i;
    const int j9 = j * 9;

    const float* __restrict__ base = x + (size_t)wid * (SEQ * 64);
    float M = base[lane];                      // M_1 = X_1

    #pragma unroll 1
    for (int k = 1; k < SEQ; ++k) {
        const float Xk = base[(k << 6) + lane];
        const float wk = 1.0f / (float)(k + 1);

        // ---- L = chol(M), lower triangular (upper lanes zeroed) ----
        float L = M;
        #pragma unroll
        for (int kk = 0; kk < 8; ++kk) {
            const float piv = bp(L, kk * 9);
            const float rp  = rcpf(piv);
            const float rd  = rsqf(piv);
            const float aik = bp(L, i8 + kk);
            const float ajk = bp(L, j8 + kk);
            const bool  upd = (i > kk) & (j > kk);
            float nv = upd ? fmaf(-aik * rp, ajk, L) : L;
            L = (j == kk) ? L * rd : nv;
        }
        L = (i >= j) ? L : 0.0f;
        const float rld = rcpf(bp(L, j9));      // lane (i,j) holds 1/L_jj

        // ---- W = L^{-1} Xk (forward substitution, lanes parallel over j)
        float W = Xk;
        #pragma unroll
        for (int m = 0; m < 8; ++m) {
            const float rl  = bp(rld, m);
            const float wm  = bp(W, (m << 3) + j) * rl;
            const float lim = bp(L, i8 + m);
            W = (i == m) ? wm : ((i > m) ? fmaf(-lim, wm, W) : W);
        }
        // ---- B^T = L^{-1} W^T  (B = W L^{-T}, symmetric) ----
        float Bv = bp(W, a_tr);
        #pragma unroll
        for (int m = 0; m < 8; ++m) {
            const float rl  = bp(rld, m);
            const float wm  = bp(Bv, (m << 3) + j) * rl;
            const float lim = bp(L, i8 + m);
            Bv = (i == m) ? wm : ((i > m) ? fmaf(-lim, wm, Bv) : Bv);
        }
        Bv = 0.5f * (Bv + bp(Bv, a_tr));

        // ---- fractional power: B^wk = V diag(lam^wk) V^T ----
        float V2;
        eigh8<5>(Bv, V2, i, j);
        const float lam = fmaxf(bp(Bv, j9), EPSF);
        const float pw  = exp2f(wk * log2f(lam));

        // ---- M' = (L V2) diag(pw) (L V2)^T ----
        float T = 0.0f;
        #pragma unroll
        for (int kk = 0; kk < 8; ++kk)
            T = fmaf(bp(L, i8 + kk), bp(V2, (kk << 3) + j), T);
        const float Tp = T * pw;
        float Mn = 0.0f;
        #pragma unroll
        for (int kk = 0; kk < 8; ++kk)
            Mn = fmaf(bp(Tp, i8 + kk), bp(T, j8 + kk), Mn);
        M = 0.5f * (Mn + bp(Mn, a_tr));
    }

    g_fm[(wid << 6) + lane] = M;
}

// ---------------- Phase 2: GL metric distances ----------------------------
__global__ void __launch_bounds__(256)
dist_kernel(const float* __restrict__ x, float* __restrict__ out) {
    const int wid  = (blockIdx.x << 2) + (threadIdx.x >> 6);   // matrix id
    const int lane = threadIdx.x & 63;
    const int i = lane >> 3, j = lane & 7;
    const int i8 = i << 3, j8 = j << 3;
    const int chain = wid >> 8;                                // / SEQ

    float Xw = x[(size_t)wid * 64 + lane];
    float Yv = g_fm[(chain << 6) + lane];

    // A = X^{-1} FM via pivot-free Gauss-Jordan (X SPD, well-conditioned)
    #pragma unroll
    for (int k = 0; k < 8; ++k) {
        const float pr  = rcpf(bp(Xw, k * 9));
        const float xk  = bp(Xw, (k << 3) + j) * pr;
        const float yk  = bp(Yv, (k << 3) + j) * pr;
        const float xik = bp(Xw, i8 + k);
        const bool  isk = (i == k);
        Xw = isk ? xk : fmaf(-xik, xk, Xw);
        Yv = isk ? yk : fmaf(-xik, yk, Yv);
    }
    const float Av = Yv;

    // B = A^T A
    float Bv = 0.0f;
    #pragma unroll
    for (int kk = 0; kk < 8; ++kk)
        Bv = fmaf(bp(Av, (kk << 3) + i), bp(Av, (kk << 3) + j), Bv);

    // eigh(B): sigma^2 = eigvals, V = right singular vectors
    float V;
    eigh8<5>(Bv, V, i, j);
    const float sig2 = fmaxf(bp(Bv, j * 9), 1e-20f);
    const float rsig = rsqf(sig2);
    const float lsj  = 0.5f * logf(sig2);      // log(sigma_j), sigma >= 1e-10

    // U = A V Sigma^{-1}
    float AV = 0.0f;
    #pragma unroll
    for (int kk = 0; kk < 8; ++kk)
        AV = fmaf(bp(Av, i8 + kk), bp(V, (kk << 3) + j), AV);
    const float U = AV * rsig;

    // W = V^T U ; dist = sum_ij ls_i ls_j W_ij W_ji
    float W = 0.0f;
    #pragma unroll
    for (int kk = 0; kk < 8; ++kk)
        W = fmaf(bp(V, (kk << 3) + i), bp(U, (kk << 3) + j), W);
    const float Wt  = bp(W, j8 + i);
    const float lsi = bp(lsj, j8 + i);

    float contrib = lsi * lsj * W * Wt;
    #pragma unroll
    for (int off = 32; off; off >>= 1)
        contrib += __shfl_xor(contrib, off, 64);

    if (lane == 0) out[wid] = contrib;
}

extern "C" void kernel_launch(void* const* d_in, const int* in_sizes, int n_in,
                              void* d_out, int out_size, void* d_ws, size_t ws_size,
                              hipStream_t stream) {
    const float* x = (const float*)d_in[0];
    float* out = (float*)d_out;
    (void)in_sizes; (void)n_in; (void)d_ws; (void)ws_size; (void)out_size;

    // Phase 1: 2048 chains, 1 wave each, 4 waves/block
    hipLaunchKernelGGL(fm_kernel, dim3(NCHAIN / 4), dim3(256), 0, stream, x);
    // Phase 2: 524288 matrices, 1 wave each
    hipLaunchKernelGGL(dist_kernel, dim3(NMAT / 4), dim3(256), 0, stream, x, out);
}

// Round 3
// 4070.509 us; speedup vs baseline: 2.4964x; 1.0499x over previous
//
#include <hip/hip_runtime.h>
#include <stdint.h>

// Problem constants (B=32, C1=64, C2=16, C3=16, N=8)
#define EPSF    1e-10f
#define NCHAIN  2048        // B*C1
#define SEQ     256         // C2*C3
#define NMAT    (NCHAIN*SEQ)

// Fréchet means live here between the two kernels (512 KB, fully
// rewritten by fm_kernel on every call -> deterministic).
__device__ float g_fm[NCHAIN * 64];

__device__ __forceinline__ float rcpf(float x) { return __builtin_amdgcn_rcpf(x); }
__device__ __forceinline__ float rsqf(float x) { return __builtin_amdgcn_rsqf(x); }
__device__ __forceinline__ float exp2f_(float x) { return __builtin_amdgcn_exp2f(x); }
__device__ __forceinline__ float log2f_(float x) { return __builtin_amdgcn_logf(x); }

// bpermute with pre-shifted (byte) address
__device__ __forceinline__ float bpf(int addr4, float v) {
    return __int_as_float(__builtin_amdgcn_ds_bpermute(addr4, __float_as_int(v)));
}
// uniform-lane broadcast (diagonal pivots): VALU-cheap, no LDS round-trip
__device__ __forceinline__ float rlf(float v, int srcLane) {
    return __int_as_float(__builtin_amdgcn_readlane(__float_as_int(v), srcLane));
}

// Round-robin tournament: entry x = partner(x) | (is_second(x) << 3)
__device__ static const uint32_t RR[7] = {
    0xABC56781u, 0xCD6718B2u, 0xE7128CD3u, 0x1238DEF4u,
    0x348EF925u, 0x58F9A346u, 0x89AB4567u
};

// Jacobi rotation params. Annihilates A[p,q]; al=c, be=+-s per sign sg.
__device__ __forceinline__ void jrot(float dpp, float dqq, float dpq, float sg,
                                     float &al, float &be) {
    const bool  tiny = fabsf(dpq) < 1e-30f;
    const float tau  = (dqq - dpp) * 0.5f * rcpf(dpq);
    float t = copysignf(rcpf(fabsf(tau) + sqrtf(fmaf(tau, tau, 1.0f))), tau);
    t = tiny ? 0.0f : t;
    al = rsqf(fmaf(t, t, 1.0f));
    be = t * al * sg;
}

// ---- latency-optimized eigh: 1 serial bpermute per round --------------
// All 10 bps per round read the PREVIOUS round's A/V -> issue in parallel.
// Row params computed directly (same formula at index i) instead of via a
// dependent transpose shuffle. Combined similarity update A <- J^T A J.
template<int NSWEEP>
__device__ __forceinline__ void eigh8_lat(float &A, float &V,
                                          const int i, const int j) {
    const int i8 = i << 3, j8 = j << 3;
    V = (i == j) ? 1.0f : 0.0f;
    int cpp[7], cqq[7], cpq[7], rpp[7], rqq[7], rpq[7];
    int axc[7], ayc[7], azc[7];
    float sgj[7], sgi[7];
    #pragma unroll
    for (int r = 0; r < 7; ++r) {
        const uint32_t tab = RR[r];
        const uint32_t ej = (tab >> (j << 2)) & 15u;
        const int  pj  = (int)(ej & 7u);
        const bool js2 = (ej & 8u) != 0u;
        const int  pc  = js2 ? pj : j, qc = js2 ? j : pj;
        cpp[r] = pc * 36; cqq[r] = qc * 36; cpq[r] = ((pc << 3) + qc) << 2;
        const uint32_t ei = (tab >> (i << 2)) & 15u;
        const int  pi_ = (int)(ei & 7u);
        const bool is2 = (ei & 8u) != 0u;
        const int  pr_ = is2 ? pi_ : i, qr_ = is2 ? i : pi_;
        rpp[r] = pr_ * 36; rqq[r] = qr_ * 36; rpq[r] = ((pr_ << 3) + qr_) << 2;
        axc[r] = (i8 + pj) << 2;
        ayc[r] = ((pi_ << 3) + j) << 2;
        azc[r] = ((pi_ << 3) + pj) << 2;
        sgj[r] = js2 ? 1.0f : -1.0f;
        sgi[r] = is2 ? 1.0f : -1.0f;
    }
    #pragma unroll 1
    for (int sw = 0; sw < NSWEEP; ++sw) {
        #pragma unroll
        for (int r = 0; r < 7; ++r) {
            const float app = bpf(cpp[r], A), aqq = bpf(cqq[r], A), apq = bpf(cpq[r], A);
            const float bpp = bpf(rpp[r], A), bqq = bpf(rqq[r], A), bpq = bpf(rpq[r], A);
            const float Ax  = bpf(axc[r], A), Ay  = bpf(ayc[r], A), Az = bpf(azc[r], A);
            const float Vc  = bpf(axc[r], V);
            float aj, bj, ai, bi;
            jrot(app, aqq, apq, sgj[r], aj, bj);
            jrot(bpp, bqq, bpq, sgi[r], ai, bi);
            const float t0 = fmaf(bj, Ax, aj * A);
            const float t1 = fmaf(bj, Az, aj * Ay);
            A = fmaf(bi, t1, ai * t0);
            V = fmaf(bj, Vc, aj * V);
        }
    }
}

// ---- throughput-optimized eigh: fewest instructions (for dist) --------
template<int NSWEEP>
__device__ __forceinline__ void eigh8_thr(float &A, float &V,
                                          const int i, const int j) {
    const int i8 = i << 3, j8 = j << 3;
    const int tr4 = (j8 + i) << 2;
    V = (i == j) ? 1.0f : 0.0f;
    int app4[7], aqq4[7], apq4[7], acl4[7], arw4[7];
    float sg[7];
    #pragma unroll
    for (int r = 0; r < 7; ++r) {
        const uint32_t tab = RR[r];
        const uint32_t ej = (tab >> (j << 2)) & 15u;
        const int  pj  = (int)(ej & 7u);
        const bool js2 = (ej & 8u) != 0u;
        const int  p   = js2 ? pj : j, q = js2 ? j : pj;
        app4[r] = p * 36; aqq4[r] = q * 36; apq4[r] = ((p << 3) + q) << 2;
        acl4[r] = (i8 + pj) << 2;
        const int pi_ = (int)((tab >> (i << 2)) & 7u);
        arw4[r] = ((pi_ << 3) + j) << 2;
        sg[r] = js2 ? 1.0f : -1.0f;
    }
    #pragma unroll 1
    for (int sw = 0; sw < NSWEEP; ++sw) {
        #pragma unroll
        for (int r = 0; r < 7; ++r) {
            const float app = bpf(app4[r], A), aqq = bpf(aqq4[r], A), apq = bpf(apq4[r], A);
            float aj, bj;
            jrot(app, aqq, apq, sg[r], aj, bj);
            const float ai = bpf(tr4, aj);
            const float bi = bpf(tr4, bj);
            const float Ac = bpf(acl4[r], A);
            A = fmaf(bj, Ac, aj * A);
            const float Ar = bpf(arw4[r], A);
            A = fmaf(bi, Ar, ai * A);
            const float Vc = bpf(acl4[r], V);
            V = fmaf(bj, Vc, aj * V);
        }
    }
}

// ---------------- Phase 1: recursive Frechet mean (sequential scan) -------
// Geodesic step, factor-invariant form with fused two-sided elimination:
//   LDL^T Gauss elimination on M while applying the SAME eliminations
//   two-sided to X:  after 8 steps  X -> L_u^{-1} X L_u^{-T},  diag(M) -> D.
//   B = D^{-1/2} (L_u^{-1} X L_u^{-T}) D^{-1/2} = L^{-1} X L^{-T},
//   L = L_u D^{1/2} (frozen columns of M, scaled).  M' = L B^w L^T.
__global__ void __launch_bounds__(256, 2)
fm_kernel(const float* __restrict__ x) {
    const int wid  = (blockIdx.x << 2) + (threadIdx.x >> 6);   // chain id
    const int lane = threadIdx.x & 63;
    const int i = lane >> 3, j = lane & 7;
    const int i32_ = i << 5, j32_ = j << 5, j4 = j << 2;
    const int i36 = i * 36, j36 = j * 36;
    const int tr4 = ((j << 3) + i) << 2;

    const float* __restrict__ base = x + (size_t)wid * (SEQ * 64);
    float M = base[lane];                      // M_1 = X_1

    #pragma unroll 1
    for (int k = 1; k < SEQ; ++k) {
        const float Xk = base[(k << 6) + lane];
        const float wk = 1.0f / (float)(k + 1);

        // ---- fused LDL^T elimination + two-sided solve (8 x 1-bp depth) --
        float Mv = M, Xv = Xk;
        #pragma unroll
        for (int kk = 0; kk < 8; ++kk) {
            const float piv = rlf(Mv, kk * 9);          // uniform: readlane
            const float Xkk = rlf(Xv, kk * 9);
            const float rp  = rcpf(piv);
            const float Mik = bpf(i32_ + (kk << 2), Mv);
            const float Mkj = bpf((kk << 5) + j4,   Mv);
            const float Xkj = bpf((kk << 5) + j4,   Xv);
            const float Xik = bpf(i32_ + (kk << 2), Xv);
            const float mi = (i > kk) ? Mik * rp : 0.0f;
            const float mj = (j > kk) ? Mkj * rp : 0.0f;
            Xv = fmaf(mi * mj, Xkk, fmaf(-mj, Xik, fmaf(-mi, Xkj, Xv)));
            Mv = ((i > kk) && (j > kk)) ? fmaf(-mi, Mkj, Mv) : Mv;
        }
        const float Di  = bpf(i36, Mv), Dj = bpf(j36, Mv);
        const float rsi = rsqf(Di),     rsj = rsqf(Dj);
        float Bv = Xv * (rsi * rsj);
        Bv = 0.5f * (Bv + bpf(tr4, Bv));                // symmetrize
        const float Lv = (i > j) ? Mv * rsj : ((i == j) ? Di * rsi : 0.0f);

        // ---- fractional power: B^wk = V2 diag(lam^wk) V2^T ----
        float V2;
        eigh8_lat<4>(Bv, V2, i, j);
        const float lam = fmaxf(bpf(j36, Bv), EPSF);
        const float pw  = exp2f_(wk * log2f_(lam));

        // ---- M' = (L V2) diag(pw) (L V2)^T ----
        float T = 0.0f;
        #pragma unroll
        for (int kk = 0; kk < 8; ++kk)
            T = fmaf(bpf(i32_ + (kk << 2), Lv), bpf((kk << 5) + j4, V2), T);
        const float Tp = T * pw;
        float Mn = 0.0f;
        #pragma unroll
        for (int kk = 0; kk < 8; ++kk)
            Mn = fmaf(bpf(i32_ + (kk << 2), Tp), bpf(j32_ + (kk << 2), T), Mn);
        M = 0.5f * (Mn + bpf(tr4, Mn));
    }

    g_fm[(wid << 6) + lane] = M;
}

// ---------------- Phase 2: GL metric distances ----------------------------
__global__ void __launch_bounds__(256, 4)
dist_kernel(const float* __restrict__ x, float* __restrict__ out) {
    const int wid  = (blockIdx.x << 2) + (threadIdx.x >> 6);   // matrix id
    const int lane = threadIdx.x & 63;
    const int i = lane >> 3, j = lane & 7;
    const int i32_ = i << 5, j32_ = j << 5, j4 = j << 2, i4 = i << 2;
    const int tr4 = ((j << 3) + i) << 2;
    const int chain = wid >> 8;                                // / SEQ

    float Xw = x[(size_t)wid * 64 + lane];
    float Yv = g_fm[(chain << 6) + lane];

    // A = X^{-1} FM via pivot-free Gauss-Jordan (X SPD, well-conditioned)
    #pragma unroll
    for (int k = 0; k < 8; ++k) {
        const float pr  = rcpf(rlf(Xw, k * 9));
        const float xk  = bpf((k << 5) + j4, Xw) * pr;
        const float yk  = bpf((k << 5) + j4, Yv) * pr;
        const float xik = bpf(i32_ + (k << 2), Xw);
        const bool  isk = (i == k);
        Xw = isk ? xk : fmaf(-xik, xk, Xw);
        Yv = isk ? yk : fmaf(-xik, yk, Yv);
    }
    const float Av = Yv;

    // B = A^T A
    float Bv = 0.0f;
    #pragma unroll
    for (int kk = 0; kk < 8; ++kk)
        Bv = fmaf(bpf((kk << 5) + i4, Av), bpf((kk << 5) + j4, Av), Bv);

    // eigh(B): sigma^2 = eigvals, V = right singular vectors
    float V;
    eigh8_thr<4>(Bv, V, i, j);
    const float sig2 = fmaxf(bpf(j * 36, Bv), 1e-20f);
    const float rsig = rsqf(sig2);
    const float lsj  = 0.34657359028f * log2f_(sig2);  // log(sigma_j)

    // U = A V Sigma^{-1}
    float AV = 0.0f;
    #pragma unroll
    for (int kk = 0; kk < 8; ++kk)
        AV = fmaf(bpf(i32_ + (kk << 2), Av), bpf((kk << 5) + j4, V), AV);
    const float U = AV * rsig;

    // W = V^T U ; dist = sum_ij ls_i ls_j W_ij W_ji
    float W = 0.0f;
    #pragma unroll
    for (int kk = 0; kk < 8; ++kk)
        W = fmaf(bpf((kk << 5) + i4, V), bpf((kk << 5) + j4, U), W);
    const float Wt  = bpf(tr4, W);
    const float lsi = bpf(tr4, lsj);

    float contrib = lsi * lsj * W * Wt;
    #pragma unroll
    for (int off = 32; off; off >>= 1)
        contrib += __shfl_xor(contrib, off, 64);

    if (lane == 0) out[wid] = contrib;
}

extern "C" void kernel_launch(void* const* d_in, const int* in_sizes, int n_in,
                              void* d_out, int out_size, void* d_ws, size_t ws_size,
                              hipStream_t stream) {
    const float* x = (const float*)d_in[0];
    float* out = (float*)d_out;
    (void)in_sizes; (void)n_in; (void)d_ws; (void)ws_size; (void)out_size;

    // Phase 1: 2048 chains, 1 wave each, 4 waves/block
    hipLaunchKernelGGL(fm_kernel, dim3(NCHAIN / 4), dim3(256), 0, stream, x);
    // Phase 2: 524288 matrices, 1 wave each
    hipLaunchKernelGGL(dist_kernel, dim3(NMAT / 4), dim3(256), 0, stream, x, out);
}

// Round 4
// 3629.206 us; speedup vs baseline: 2.8000x; 1.1216x over previous
//
#include <hip/hip_runtime.h>
#include <stdint.h>

// Problem constants (B=32, C1=64, C2=16, C3=16, N=8)
#define EPSF    1e-10f
#define NCHAIN  2048        // B*C1
#define SEQ     256         // C2*C3
#define NMAT    (NCHAIN*SEQ)

// Fréchet means live here between the two kernels (512 KB, fully
// rewritten by fm_kernel on every call -> deterministic).
__device__ float g_fm[NCHAIN * 64];

__device__ __forceinline__ float rcpf(float x) { return __builtin_amdgcn_rcpf(x); }
__device__ __forceinline__ float rsqf(float x) { return __builtin_amdgcn_rsqf(x); }
__device__ __forceinline__ float exp2f_(float x) { return __builtin_amdgcn_exp2f(x); }
__device__ __forceinline__ float log2f_(float x) { return __builtin_amdgcn_logf(x); }

// bpermute with pre-shifted (byte) address
__device__ __forceinline__ float bpf(int addr4, float v) {
    return __int_as_float(__builtin_amdgcn_ds_bpermute(addr4, __float_as_int(v)));
}
// uniform-lane broadcast (diagonal pivots)
__device__ __forceinline__ float rlf(float v, int srcLane) {
    return __int_as_float(__builtin_amdgcn_readlane(__float_as_int(v), srcLane));
}

// Jacobi rotation params for pair {j, j^m}, symmetric per-lane form.
// Inputs: dj = A[j,j], dm = A[j^m,j^m], apq = A[j,j^m], sg = tie-break sign
// (+1 if this index is the pair's "second", -1 otherwise).
// Outputs: c (cos), bs (signed sin coefficient for the partner column):
//   col j' = c*col_j + bs*col_{j^m},  antisymmetric in the pair.
// 2 transcendentals, branch-free, exact identity on converged pairs.
__device__ __forceinline__ void jrot2(float dj, float dm, float apq, float sg,
                                      float &c, float &bs) {
    const float dd = dj - dm;
    const float h  = apq + apq;
    const float r2 = fmaf(dd, dd, fmaf(h, h, 1e-36f));
    const float rr = rsqf(r2);                          // 1/r
    const float c2 = fmaf(0.5f * fabsf(dd), rr, 0.5f);  // cos^2 = (1+|d|/r)/2
    const float ic = rsqf(c2);                          // 1/c
    const float chi = (dd != 0.0f) ? copysignf(1.0f, dd) : sg;
    const bool  tiny = r2 < 1e-33f;
    c  = tiny ? 1.0f : c2 * ic;                         // sqrt(c2)
    bs = tiny ? 0.0f : apq * chi * rr * ic;             // s*sign, s=|apq|/(r*c)
}

// ---- latency-optimized eigh (fm): XOR-pair rounds, 1-bp serial depth ----
// Round m pairs index x with x^m. All 10 DS reads per round read the
// PREVIOUS round's A/V -> issue in parallel. Addresses are base^const.
template<int NSWEEP>
__device__ __forceinline__ void eigh8_lat(float &A, float &V, const int lane,
                                          const int lane4, const int i36,
                                          const int j36) {
    V = (i36 == j36) ? 1.0f : 0.0f;
    #pragma unroll 1
    for (int sw = 0; sw < NSWEEP; ++sw) {
        #pragma unroll
        for (int m = 1; m <= 7; ++m) {
            const int m4 = m << 2, m32 = m << 5, m36 = m * 36;
            const int hb = (m & 4) ? 4 : ((m & 2) ? 2 : 1);
            // column-pair params (pair {j, j^m})
            const float dj  = bpf(j36,        A);
            const float dmj = bpf(j36 ^ m36,  A);
            const float aqj = bpf(j36 ^ m4,   A);
            // row-pair params (pair {i, i^m})
            const float di  = bpf(i36,        A);
            const float dmi = bpf(i36 ^ m36,  A);
            const float aqi = bpf(i36 ^ m4,   A);
            // neighbors (prev A) + V partner
            const float Ax = bpf(lane4 ^ m4,  A);   // A[i,   j^m]
            const float Ay = bpf(lane4 ^ m32, A);   // A[i^m, j  ]
            const float Az = bpf(lane4 ^ m36, A);   // A[i^m, j^m]
            const float Vc = bpf(lane4 ^ m4,  V);
            const float sgj = (lane & hb)        ? 1.0f : -1.0f;
            const float sgi = (lane & (hb << 3)) ? 1.0f : -1.0f;
            float aj, bj, ai, bi;
            jrot2(dj, dmj, aqj, sgj, aj, bj);
            jrot2(di, dmi, aqi, sgi, ai, bi);
            const float t0 = fmaf(bj, Ax, aj * A);   // col update, row i
            const float t1 = fmaf(bj, Az, aj * Ay);  // col update, row i^m
            A = fmaf(bi, t1, ai * t0);               // row update
            V = fmaf(bj, Vc, aj * V);
        }
    }
}

// ---- throughput-optimized eigh (dist): 1 jrot/round, transpose params ----
template<int NSWEEP>
__device__ __forceinline__ void eigh8_thr(float &A, float &V, const int lane,
                                          const int lane4, const int j36,
                                          const int tr4) {
    V = ((lane4 >> 5) == ((lane4 >> 2) & 7)) ? 1.0f : 0.0f;  // i==j
    #pragma unroll 1
    for (int sw = 0; sw < NSWEEP; ++sw) {
        #pragma unroll
        for (int m = 1; m <= 7; ++m) {
            const int m4 = m << 2, m32 = m << 5, m36 = m * 36;
            const int hb = (m & 4) ? 4 : ((m & 2) ? 2 : 1);
            const float dj  = bpf(j36,       A);
            const float dmj = bpf(j36 ^ m36, A);
            const float aqj = bpf(j36 ^ m4,  A);
            const float sgj = (lane & hb) ? 1.0f : -1.0f;
            float aj, bj;
            jrot2(dj, dmj, aqj, sgj, aj, bj);
            const float ai = bpf(tr4, aj);          // row params = transpose
            const float bi = bpf(tr4, bj);
            const float Ac = bpf(lane4 ^ m4, A);
            A = fmaf(bj, Ac, aj * A);               // A <- A J
            const float Ar = bpf(lane4 ^ m32, A);
            A = fmaf(bi, Ar, ai * A);               // A <- J^T A
            const float Vc = bpf(lane4 ^ m4, V);
            V = fmaf(bj, Vc, aj * V);
        }
    }
}

// ---------------- Phase 1: recursive Frechet mean (sequential scan) -------
// Geodesic step, factor-invariant form with fused two-sided elimination:
//   LDL^T Gauss elimination on M while applying the SAME eliminations
//   two-sided to X:  after 8 steps  X -> L_u^{-1} X L_u^{-T},  diag(M) -> D.
//   B = D^{-1/2} (L_u^{-1} X L_u^{-T}) D^{-1/2} = L^{-1} X L^{-T},
//   L = L_u D^{1/2} (frozen columns of M, scaled).  M' = L B^w L^T.
__global__ void __launch_bounds__(256, 2)
fm_kernel(const float* __restrict__ x) {
    const int wid  = (blockIdx.x << 2) + (threadIdx.x >> 6);   // chain id
    const int lane = threadIdx.x & 63;
    const int i = lane >> 3, j = lane & 7;
    const int lane4 = lane << 2;
    const int i32_ = i << 5, j4 = j << 2, j32_ = j << 5;
    const int i36 = i * 36, j36 = j * 36;
    const int tr4 = ((j << 3) + i) << 2;

    const float* __restrict__ base = x + (size_t)wid * (SEQ * 64);
    float M = base[lane];                      // M_1 = X_1

    #pragma unroll 1
    for (int k = 1; k < SEQ; ++k) {
        const float Xk = base[(k << 6) + lane];
        const float wk = 1.0f / (float)(k + 1);

        // ---- fused LDL^T elimination + two-sided solve (8 x 1-bp depth) --
        float Mv = M, Xv = Xk;
        #pragma unroll
        for (int kk = 0; kk < 8; ++kk) {
            const float piv = rlf(Mv, kk * 9);          // uniform: readlane
            const float Xkk = rlf(Xv, kk * 9);
            const float rp  = rcpf(piv);
            const float Mik = bpf(i32_ + (kk << 2), Mv);
            const float Mkj = bpf((kk << 5) + j4,   Mv);
            const float Xkj = bpf((kk << 5) + j4,   Xv);
            const float Xik = bpf(i32_ + (kk << 2), Xv);
            const float mi = (i > kk) ? Mik * rp : 0.0f;
            const float mj = (j > kk) ? Mkj * rp : 0.0f;
            Xv = fmaf(mi * mj, Xkk, fmaf(-mj, Xik, fmaf(-mi, Xkj, Xv)));
            Mv = ((i > kk) && (j > kk)) ? fmaf(-mi, Mkj, Mv) : Mv;
        }
        const float Di  = bpf(i36, Mv), Dj = bpf(j36, Mv);
        const float rsi = rsqf(Di),     rsj = rsqf(Dj);
        float Bv = Xv * (rsi * rsj);
        Bv = 0.5f * (Bv + bpf(tr4, Bv));                // symmetrize
        const float Lv = (i > j) ? Mv * rsj : ((i == j) ? Di * rsi : 0.0f);

        // ---- fractional power: B^wk = V2 diag(lam^wk) V2^T ----
        float V2;
        eigh8_lat<4>(Bv, V2, lane, lane4, i36, j36);
        const float lam = fmaxf(bpf(j36, Bv), EPSF);
        const float pw  = exp2f_(wk * log2f_(lam));

        // ---- M' = (L V2) diag(pw) (L V2)^T ----
        float T = 0.0f;
        #pragma unroll
        for (int kk = 0; kk < 8; ++kk)
            T = fmaf(bpf(i32_ + (kk << 2), Lv), bpf((kk << 5) + j4, V2), T);
        const float Tp = T * pw;
        float Mn = 0.0f;
        #pragma unroll
        for (int kk = 0; kk < 8; ++kk)
            Mn = fmaf(bpf(i32_ + (kk << 2), Tp), bpf(j32_ + (kk << 2), T), Mn);
        M = 0.5f * (Mn + bpf(tr4, Mn));
    }

    g_fm[(wid << 6) + lane] = M;
}

// ---------------- Phase 2: GL metric distances ----------------------------
__global__ void __launch_bounds__(256, 4)
dist_kernel(const float* __restrict__ x, float* __restrict__ out) {
    const int wid  = (blockIdx.x << 2) + (threadIdx.x >> 6);   // matrix id
    const int lane = threadIdx.x & 63;
    const int i = lane >> 3, j = lane & 7;
    const int lane4 = lane << 2;
    const int i32_ = i << 5, j4 = j << 2, i4 = i << 2;
    const int j36 = j * 36;
    const int tr4 = ((j << 3) + i) << 2;
    const int chain = wid >> 8;                                // / SEQ

    float Xw = x[(size_t)wid * 64 + lane];
    float Yv = g_fm[(chain << 6) + lane];

    // A = X^{-1} FM via pivot-free Gauss-Jordan (X SPD, well-conditioned)
    #pragma unroll
    for (int k = 0; k < 8; ++k) {
        const float pr  = rcpf(rlf(Xw, k * 9));
        const float xk  = bpf((k << 5) + j4, Xw) * pr;
        const float yk  = bpf((k << 5) + j4, Yv) * pr;
        const float xik = bpf(i32_ + (k << 2), Xw);
        const bool  isk = (i == k);
        Xw = isk ? xk : fmaf(-xik, xk, Xw);
        Yv = isk ? yk : fmaf(-xik, yk, Yv);
    }
    const float Av = Yv;

    // B = A^T A
    float Bv = 0.0f;
    #pragma unroll
    for (int kk = 0; kk < 8; ++kk)
        Bv = fmaf(bpf((kk << 5) + i4, Av), bpf((kk << 5) + j4, Av), Bv);

    // eigh(B): sigma^2 = eigvals, V = right singular vectors
    float V;
    eigh8_thr<4>(Bv, V, lane, lane4, j36, tr4);
    const float sig2 = fmaxf(bpf(j36, Bv), 1e-20f);
    const float rsig = rsqf(sig2);
    const float lsj  = 0.34657359028f * log2f_(sig2);  // log(sigma_j)

    // U = A V Sigma^{-1}
    float AV = 0.0f;
    #pragma unroll
    for (int kk = 0; kk < 8; ++kk)
        AV = fmaf(bpf(i32_ + (kk << 2), Av), bpf((kk << 5) + j4, V), AV);
    const float U = AV * rsig;

    // W = V^T U ; dist = sum_ij ls_i ls_j W_ij W_ji
    float W = 0.0f;
    #pragma unroll
    for (int kk = 0; kk < 8; ++kk)
        W = fmaf(bpf((kk << 5) + i4, V), bpf((kk << 5) + j4, U), W);
    const float Wt  = bpf(tr4, W);
    const float lsi = bpf(tr4, lsj);

    float contrib = lsi * lsj * W * Wt;
    #pragma unroll
    for (int off = 32; off; off >>= 1)
        contrib += __shfl_xor(contrib, off, 64);

    if (lane == 0) out[wid] = contrib;
}

extern "C" void kernel_launch(void* const* d_in, const int* in_sizes, int n_in,
                              void* d_out, int out_size, void* d_ws, size_t ws_size,
                              hipStream_t stream) {
    const float* x = (const float*)d_in[0];
    float* out = (float*)d_out;
    (void)in_sizes; (void)n_in; (void)d_ws; (void)ws_size; (void)out_size;

    // Phase 1: 2048 chains, 1 wave each, 4 waves/block
    hipLaunchKernelGGL(fm_kernel, dim3(NCHAIN / 4), dim3(256), 0, stream, x);
    // Phase 2: 524288 matrices, 1 wave each
    hipLaunchKernelGGL(dist_kernel, dim3(NMAT / 4), dim3(256), 0, stream, x, out);
}

// Round 5
// 2859.225 us; speedup vs baseline: 3.5540x; 1.2693x over previous
//
#include <hip/hip_runtime.h>
#include <stdint.h>

// Problem constants (B=32, C1=64, C2=16, C3=16, N=8)
#define EPSF    1e-10f
#define NCHAIN  2048        // B*C1
#define SEQ     256         // C2*C3
#define NMAT    (NCHAIN*SEQ)

// Fréchet means live here between the two kernels (512 KB, fully
// rewritten by fm_kernel on every call -> deterministic).
__device__ float g_fm[NCHAIN * 64];

__device__ __forceinline__ float rcpf(float x) { return __builtin_amdgcn_rcpf(x); }
__device__ __forceinline__ float rsqf(float x) { return __builtin_amdgcn_rsqf(x); }
__device__ __forceinline__ float exp2f_(float x) { return __builtin_amdgcn_exp2f(x); }
__device__ __forceinline__ float log2f_(float x) { return __builtin_amdgcn_logf(x); }

// bpermute with pre-shifted (byte) address
__device__ __forceinline__ float bpf(int addr4, float v) {
    return __int_as_float(__builtin_amdgcn_ds_bpermute(addr4, __float_as_int(v)));
}
// uniform-lane broadcast (diagonal pivots)
__device__ __forceinline__ float rlf(float v, int srcLane) {
    return __int_as_float(__builtin_amdgcn_readlane(__float_as_int(v), srcLane));
}
// lane-XOR shuffle with immediate pattern (ds_swizzle BitMode), mask < 32:
// zero address VALU, zero address VGPR.
template<int MASK>
__device__ __forceinline__ float sxf(float v) {
    static_assert(MASK > 0 && MASK < 32, "swizzle mask");
    return __int_as_float(__builtin_amdgcn_ds_swizzle(
        __float_as_int(v), (MASK << 10) | 0x1F));
}

// Jacobi rotation params for pair {j, j^m}. dj = own diag, dm = partner
// diag, apq = pair off-diagonal, sg = tie-break sign (+1 for pair-second).
// col_j' = c*col_j + bs*col_{j^m}, antisymmetric in the pair.
__device__ __forceinline__ void jrot2(float dj, float dm, float apq, float sg,
                                      float &c, float &bs) {
    const float dd = dj - dm;
    const float h  = apq + apq;
    const float r2 = fmaf(dd, dd, fmaf(h, h, 1e-36f));
    const float rr = rsqf(r2);                          // 1/r
    const float c2 = fmaf(0.5f * fabsf(dd), rr, 0.5f);  // cos^2 = (1+|d|/r)/2
    const float ic = rsqf(c2);                          // 1/c
    const float chi = (dd != 0.0f) ? copysignf(1.0f, dd) : sg;
    const bool  tiny = r2 < 1e-33f;
    c  = tiny ? 1.0f : c2 * ic;                         // sqrt(c2)
    bs = tiny ? 0.0f : apq * chi * rr * ic;             // s*sign
}

// ---- fm round: 1-bp serial depth, diag-in-register, T accumulation ------
// A: active matrix; T: accumulates T <- T*J (caller inits, e.g. T=L);
// D/DT: column-/row-replicated diagonal of A, maintained in-register.
template<int M>
__device__ __forceinline__ void jround_lat(float &A, float &T, float &D,
                                           float &DT, const int lane,
                                           const int lane4, const int i36,
                                           const int j36) {
    constexpr int HB = (M & 4) ? 4 : ((M & 2) ? 2 : 1);
    const float dmj = sxf<M>(D);
    const float aqj = bpf(j36 ^ (M << 2), A);   // A[j, j^M]
    const float aqi = bpf(i36 ^ (M << 2), A);   // A[i, i^M]
    const float Ax  = sxf<M>(A);                // A[i,   j^M]
    const float Tc  = sxf<M>(T);
    float dmi, Ay, Az;
    if constexpr ((M << 3) < 32) {
        dmi = sxf<(M << 3)>(DT);
        Ay  = sxf<(M << 3)>(A);                 // A[i^M, j  ]
        Az  = sxf<(M * 9)>(A);                  // A[i^M, j^M]
    } else {
        dmi = bpf(lane4 ^ (M << 5), DT);
        Ay  = bpf(lane4 ^ (M << 5), A);
        Az  = bpf(lane4 ^ (M * 36), A);
    }
    const float sgj = (lane & HB)        ? 1.0f : -1.0f;
    const float sgi = (lane & (HB << 3)) ? 1.0f : -1.0f;
    float aj, bj, ai, bi;
    jrot2(D,  dmj, aqj, sgj, aj, bj);
    jrot2(DT, dmi, aqi, sgi, ai, bi);
    const float t0 = fmaf(bj, Ax, aj * A);
    const float t1 = fmaf(bj, Az, aj * Ay);
    A = fmaf(bi, t1, ai * t0);
    T = fmaf(bj, Tc, aj * T);
    // diagonal updates mirror the diagonal-lane A formula exactly
    const float d0 = fmaf(bj, aqj, aj * D);
    const float d1 = fmaf(bj, dmj, aj * aqj);
    D = fmaf(bj, d1, aj * d0);
    const float e0 = fmaf(bi, aqi, ai * DT);
    const float e1 = fmaf(bi, dmi, ai * aqi);
    DT = fmaf(bi, e1, ai * e0);
}

// ---- dist round: throughput form (transpose row params), diag-in-reg ----
template<int M>
__device__ __forceinline__ void jround_thr(float &A, float &V, float &D,
                                           const int lane, const int lane4,
                                           const int j36, const int tr4) {
    constexpr int HB = (M & 4) ? 4 : ((M & 2) ? 2 : 1);
    const float dmj = sxf<M>(D);
    const float aqj = bpf(j36 ^ (M << 2), A);
    const float sgj = (lane & HB) ? 1.0f : -1.0f;
    float aj, bj;
    jrot2(D, dmj, aqj, sgj, aj, bj);
    const float ai = bpf(tr4, aj);              // row params = transpose
    const float bi = bpf(tr4, bj);
    const float Ac = sxf<M>(A);
    A = fmaf(bj, Ac, aj * A);                   // A <- A J
    float Ar;
    if constexpr ((M << 3) < 32) Ar = sxf<(M << 3)>(A);
    else                         Ar = bpf(lane4 ^ (M << 5), A);
    A = fmaf(bi, Ar, ai * A);                   // A <- J^T A
    const float Vc = sxf<M>(V);
    V = fmaf(bj, Vc, aj * V);
    const float d0 = fmaf(bj, aqj, aj * D);
    const float d1 = fmaf(bj, dmj, aj * aqj);
    D = fmaf(bj, d1, aj * d0);
}

// ---------------- Phase 1: recursive Frechet mean (sequential scan) -------
// Geodesic step, factor-invariant form with fused two-sided elimination:
//   LDL^T Gauss elimination on M while applying the SAME eliminations
//   two-sided to X:  after 8 steps  X -> L_u^{-1} X L_u^{-T},  diag(M) -> D.
//   B = D^{-1/2} (L_u^{-1} X L_u^{-T}) D^{-1/2} = L^{-1} X L^{-T},
//   L = L_u D^{1/2}.  M' = (L V2) diag(lam^w) (L V2)^T, T=L*V2 accumulated
//   inside the Jacobi loop.
__global__ void __launch_bounds__(256, 2)
fm_kernel(const float* __restrict__ x) {
    const int wid  = (blockIdx.x << 2) + (threadIdx.x >> 6);   // chain id
    const int lane = threadIdx.x & 63;
    const int i = lane >> 3, j = lane & 7;
    const int lane4 = lane << 2;
    const int i32_ = i << 5, j4 = j << 2, j32_ = j << 5;
    const int i36 = i * 36, j36 = j * 36;
    const int tr4 = ((j << 3) + i) << 2;

    const float* __restrict__ base = x + (size_t)wid * (SEQ * 64);
    float M = base[lane];                      // M_1 = X_1

    #pragma unroll 1
    for (int k = 1; k < SEQ; ++k) {
        const float Xk = base[(k << 6) + lane];
        const float wk = 1.0f / (float)(k + 1);

        // ---- fused LDL^T elimination + two-sided solve (8 x 1-bp depth) --
        float Mv = M, Xv = Xk;
        #pragma unroll
        for (int kk = 0; kk < 8; ++kk) {
            const float piv = rlf(Mv, kk * 9);          // uniform: readlane
            const float Xkk = rlf(Xv, kk * 9);
            const float rp  = rcpf(piv);
            const float Mik = bpf(i32_ + (kk << 2), Mv);
            const float Mkj = bpf((kk << 5) + j4,   Mv);
            const float Xkj = bpf((kk << 5) + j4,   Xv);
            const float Xik = bpf(i32_ + (kk << 2), Xv);
            const float mi = (i > kk) ? Mik * rp : 0.0f;
            const float mj = (j > kk) ? Mkj * rp : 0.0f;
            Xv = fmaf(mi * mj, Xkk, fmaf(-mj, Xik, fmaf(-mi, Xkj, Xv)));
            Mv = ((i > kk) && (j > kk)) ? fmaf(-mi, Mkj, Mv) : Mv;
        }
        const float Di  = bpf(i36, Mv), Dj = bpf(j36, Mv);
        const float rsi = rsqf(Di),     rsj = rsqf(Dj);
        float Bv = Xv * (rsi * rsj);
        Bv = 0.5f * (Bv + bpf(tr4, Bv));                // symmetrize
        const float Lv = (i > j) ? Mv * rsj : ((i == j) ? Di * rsi : 0.0f);

        // ---- eigh(B) with T = L*V2 accumulated, diag in registers ----
        float D = bpf(j36, Bv);                         // col-replicated diag
        float DT = bpf(i36, Bv);                        // row-replicated diag
        float T = Lv;
        #pragma unroll 1
        for (int sw = 0; sw < 4; ++sw) {
            jround_lat<1>(Bv, T, D, DT, lane, lane4, i36, j36);
            jround_lat<2>(Bv, T, D, DT, lane, lane4, i36, j36);
            jround_lat<3>(Bv, T, D, DT, lane, lane4, i36, j36);
            jround_lat<4>(Bv, T, D, DT, lane, lane4, i36, j36);
            jround_lat<5>(Bv, T, D, DT, lane, lane4, i36, j36);
            jround_lat<6>(Bv, T, D, DT, lane, lane4, i36, j36);
            jround_lat<7>(Bv, T, D, DT, lane, lane4, i36, j36);
        }
        const float pw = exp2f_(wk * log2f_(fmaxf(D, EPSF)));  // lam^wk, col-repl

        // ---- M' = T diag(pw) T^T  (bitwise symmetric accumulation) ----
        float Mn = 0.0f;
        #pragma unroll
        for (int kk = 0; kk < 8; ++kk) {
            const float Ti = bpf(i32_ + (kk << 2), T);
            const float Tj = bpf(j32_ + (kk << 2), T);
            Mn = fmaf(rlf(pw, kk), Ti * Tj, Mn);
        }
        M = Mn;                                          // exactly symmetric
    }

    g_fm[(wid << 6) + lane] = M;
}

// ---------------- Phase 2: GL metric distances ----------------------------
__global__ void __launch_bounds__(256, 4)
dist_kernel(const float* __restrict__ x, float* __restrict__ out) {
    const int wid  = (blockIdx.x << 2) + (threadIdx.x >> 6);   // matrix id
    const int lane = threadIdx.x & 63;
    const int i = lane >> 3, j = lane & 7;
    const int lane4 = lane << 2;
    const int i32_ = i << 5, j4 = j << 2, i4 = i << 2;
    const int j36 = j * 36;
    const int tr4 = ((j << 3) + i) << 2;
    const int chain = wid >> 8;                                // / SEQ

    float Xw = x[(size_t)wid * 64 + lane];
    float Yv = g_fm[(chain << 6) + lane];

    // A = X^{-1} FM via pivot-free Gauss-Jordan (X SPD, well-conditioned)
    #pragma unroll
    for (int k = 0; k < 8; ++k) {
        const float pr  = rcpf(rlf(Xw, k * 9));
        const float xk  = bpf((k << 5) + j4, Xw) * pr;
        const float yk  = bpf((k << 5) + j4, Yv) * pr;
        const float xik = bpf(i32_ + (k << 2), Xw);
        const bool  isk = (i == k);
        Xw = isk ? xk : fmaf(-xik, xk, Xw);
        Yv = isk ? yk : fmaf(-xik, yk, Yv);
    }
    const float Av = Yv;

    // B = A^T A (bitwise symmetric)
    float Bv = 0.0f;
    #pragma unroll
    for (int kk = 0; kk < 8; ++kk)
        Bv = fmaf(bpf((kk << 5) + i4, Av), bpf((kk << 5) + j4, Av), Bv);

    // eigh(B): sigma^2 = eigvals (in D), V = right singular vectors
    float V = (i == j) ? 1.0f : 0.0f;
    float D = bpf(j36, Bv);
    #pragma unroll 1
    for (int sw = 0; sw < 4; ++sw) {
        jround_thr<1>(Bv, V, D, lane, lane4, j36, tr4);
        jround_thr<2>(Bv, V, D, lane, lane4, j36, tr4);
        jround_thr<3>(Bv, V, D, lane, lane4, j36, tr4);
        jround_thr<4>(Bv, V, D, lane, lane4, j36, tr4);
        jround_thr<5>(Bv, V, D, lane, lane4, j36, tr4);
        jround_thr<6>(Bv, V, D, lane, lane4, j36, tr4);
        jround_thr<7>(Bv, V, D, lane, lane4, j36, tr4);
    }
    const float sig2 = fmaxf(D, 1e-20f);
    const float rsig = rsqf(sig2);
    const float lsj  = 0.34657359028f * log2f_(sig2);  // log(sigma_j)

    // U = A V Sigma^{-1}
    float AV = 0.0f;
    #pragma unroll
    for (int kk = 0; kk < 8; ++kk)
        AV = fmaf(bpf(i32_ + (kk << 2), Av), bpf((kk << 5) + j4, V), AV);
    const float U = AV * rsig;

    // W = V^T U ; dist = sum_ij ls_i ls_j W_ij W_ji
    float W = 0.0f;
    #pragma unroll
    for (int kk = 0; kk < 8; ++kk)
        W = fmaf(bpf((kk << 5) + i4, V), bpf((kk << 5) + j4, U), W);
    const float Wt  = bpf(tr4, W);
    const float lsi = bpf(tr4, lsj);

    float contrib = lsi * lsj * W * Wt;
    #pragma unroll
    for (int off = 32; off; off >>= 1)
        contrib += __shfl_xor(contrib, off, 64);

    if (lane == 0) out[wid] = contrib;
}

extern "C" void kernel_launch(void* const* d_in, const int* in_sizes, int n_in,
                              void* d_out, int out_size, void* d_ws, size_t ws_size,
                              hipStream_t stream) {
    const float* x = (const float*)d_in[0];
    float* out = (float*)d_out;
    (void)in_sizes; (void)n_in; (void)d_ws; (void)ws_size; (void)out_size;

    // Phase 1: 2048 chains, 1 wave each, 4 waves/block
    hipLaunchKernelGGL(fm_kernel, dim3(NCHAIN / 4), dim3(256), 0, stream, x);
    // Phase 2: 524288 matrices, 1 wave each
    hipLaunchKernelGGL(dist_kernel, dim3(NMAT / 4), dim3(256), 0, stream, x, out);
}

// Round 6
// 2231.256 us; speedup vs baseline: 4.5542x; 1.2814x over previous
//
#include <hip/hip_runtime.h>
#include <stdint.h>

// Problem constants (B=32, C1=64, C2=16, C3=16, N=8)
#define EPSF    1e-10f
#define NCHAIN  2048        // B*C1
#define SEQ     256         // C2*C3
#define NMAT    (NCHAIN*SEQ)

// Fréchet means live here between the two kernels (512 KB, fully
// rewritten by fm_kernel on every call -> deterministic).
__device__ float g_fm[NCHAIN * 64];

__device__ __forceinline__ float rcpf(float x) { return __builtin_amdgcn_rcpf(x); }
__device__ __forceinline__ float rsqf(float x) { return __builtin_amdgcn_rsqf(x); }
__device__ __forceinline__ float exp2f_(float x) { return __builtin_amdgcn_exp2f(x); }
__device__ __forceinline__ float log2f_(float x) { return __builtin_amdgcn_logf(x); }

// bpermute with pre-shifted (byte) address
__device__ __forceinline__ float bpf(int addr4, float v) {
    return __int_as_float(__builtin_amdgcn_ds_bpermute(addr4, __float_as_int(v)));
}
// uniform-lane broadcast (diagonal pivots)
__device__ __forceinline__ float rlf(float v, int srcLane) {
    return __int_as_float(__builtin_amdgcn_readlane(__float_as_int(v), srcLane));
}
// lane-XOR shuffle with immediate pattern (ds_swizzle BitMode). Masks < 32:
// operates within 32-lane halves; all masks used here keep lanes in-half.
template<int MASK>
__device__ __forceinline__ float sxf(float v) {
    static_assert(MASK > 0 && MASK < 32, "swizzle mask");
    return __int_as_float(__builtin_amdgcn_ds_swizzle(
        __float_as_int(v), (MASK << 10) | 0x1F));
}

// 8-float dot from two LDS rows (4x ds_read_b128, 2-way bank alias = free)
__device__ __forceinline__ float dot8(const float* __restrict__ a,
                                      const float* __restrict__ b) {
    const float4 a0 = *reinterpret_cast<const float4*>(a);
    const float4 a1 = *reinterpret_cast<const float4*>(a + 4);
    const float4 b0 = *reinterpret_cast<const float4*>(b);
    const float4 b1 = *reinterpret_cast<const float4*>(b + 4);
    float s = a0.x * b0.x;
    s = fmaf(a0.y, b0.y, s); s = fmaf(a0.z, b0.z, s); s = fmaf(a0.w, b0.w, s);
    s = fmaf(a1.x, b1.x, s); s = fmaf(a1.y, b1.y, s); s = fmaf(a1.z, b1.z, s);
    s = fmaf(a1.w, b1.w, s);
    return s;
}

// Jacobi rotation params for pair {j, j^m}. dj = own diag, dm = partner
// diag, apq = pair off-diagonal, sg = tie-break sign (+1 for pair-second).
// col_j' = c*col_j + bs*col_{j^m}, antisymmetric in the pair.
__device__ __forceinline__ void jrot2(float dj, float dm, float apq, float sg,
                                      float &c, float &bs) {
    const float dd = dj - dm;
    const float h  = apq + apq;
    const float r2 = fmaf(dd, dd, fmaf(h, h, 1e-36f));
    const float rr = rsqf(r2);                          // 1/r
    const float c2 = fmaf(0.5f * fabsf(dd), rr, 0.5f);  // cos^2 = (1+|d|/r)/2
    const float ic = rsqf(c2);                          // 1/c
    const float chi = (dd != 0.0f) ? copysignf(1.0f, dd) : sg;
    const bool  tiny = r2 < 1e-33f;
    c  = tiny ? 1.0f : c2 * ic;                         // sqrt(c2)
    bs = tiny ? 0.0f : apq * chi * rr * ic;             // s*sign
}

// ---- unified Jacobi round: 7 DS ops, diag-in-register, accumulator W ----
// A: active symmetric matrix; W: accumulates W <- W*J (V or L*V);
// D: column-replicated diagonal of A, maintained in-register.
// Row params come from the transpose read of the column params.
template<int M>
__device__ __forceinline__ void jround(float &A, float &W, float &D,
                                       const int lane, const int lane4,
                                       const int j36, const int tr4) {
    constexpr int HB = (M & 4) ? 4 : ((M & 2) ? 2 : 1);
    const float dmj = sxf<M>(D);
    const float aqj = bpf(j36 ^ (M << 2), A);   // A[j, j^M]
    const float sgj = (lane & HB) ? 1.0f : -1.0f;
    float aj, bj;
    jrot2(D, dmj, aqj, sgj, aj, bj);
    const float ai = bpf(tr4, aj);              // row params = transpose
    const float bi = bpf(tr4, bj);
    const float Ac = sxf<M>(A);                 // A[i, j^M]
    A = fmaf(bj, Ac, aj * A);                   // A <- A J
    float Ar;                                   // A[i^M, j] (post col-update)
    if constexpr ((M << 3) < 32) Ar = sxf<(M << 3)>(A);
    else                         Ar = bpf(lane4 ^ (M << 5), A);
    A = fmaf(bi, Ar, ai * A);                   // A <- J^T A
    const float Wc = sxf<M>(W);
    W = fmaf(bj, Wc, aj * W);
    const float d0 = fmaf(bj, aqj, aj * D);     // pair-subspace diag update
    const float d1 = fmaf(bj, dmj, aj * aqj);
    D = fmaf(bj, d1, aj * d0);
}

// ---------------- Phase 1: recursive Frechet mean (sequential scan) -------
// Geodesic step, factor-invariant form with fused two-sided elimination:
//   LDL^T Gauss elimination on M while applying the SAME eliminations
//   two-sided to X:  after 8 steps  X -> L_u^{-1} X L_u^{-T},  diag(M) -> D.
//   B = D^{-1/2} (L_u^{-1} X L_u^{-T}) D^{-1/2} = L^{-1} X L^{-T},
//   L = L_u D^{1/2}.  M' = T diag(lam^w) T^T with T = L*V2 accumulated
//   inside the Jacobi loop; final matmul via wave-private LDS rows.
__global__ void __launch_bounds__(256, 2)
fm_kernel(const float* __restrict__ x) {
    __shared__ __align__(16) float sT[4][64];
    float* __restrict__ myT = sT[threadIdx.x >> 6];

    const int wid  = (blockIdx.x << 2) + (threadIdx.x >> 6);   // chain id
    const int lane = threadIdx.x & 63;
    const int i = lane >> 3, j = lane & 7;
    const int lane4 = lane << 2;
    const int i32_ = i << 5, j4 = j << 2;
    const int i36 = i * 36, j36 = j * 36;
    const int i8f = i << 3, j8f = j << 3;
    const int tr4 = ((j << 3) + i) << 2;

    const float* __restrict__ base = x + (size_t)wid * (SEQ * 64);
    float M = base[lane];                      // M_1 = X_1

    #pragma unroll 1
    for (int k = 1; k < SEQ; ++k) {
        const float Xk = base[(k << 6) + lane];
        const float wk = rcpf((float)(k + 1));

        // ---- fused LDL^T elimination + two-sided solve (8 x 1-bp depth) --
        float Mv = M, Xv = Xk;
        #pragma unroll
        for (int kk = 0; kk < 8; ++kk) {
            const float piv = rlf(Mv, kk * 9);          // uniform: readlane
            const float Xkk = rlf(Xv, kk * 9);
            const float rp  = rcpf(piv);
            const float Mik = bpf(i32_ + (kk << 2), Mv);
            const float Mkj = bpf((kk << 5) + j4,   Mv);
            const float Xkj = bpf((kk << 5) + j4,   Xv);
            const float Xik = bpf(i32_ + (kk << 2), Xv);
            const float mi = (i > kk) ? Mik * rp : 0.0f;
            const float mj = (j > kk) ? Mkj * rp : 0.0f;
            Xv = fmaf(mi * mj, Xkk, fmaf(-mj, Xik, fmaf(-mi, Xkj, Xv)));
            Mv = ((i > kk) && (j > kk)) ? fmaf(-mi, Mkj, Mv) : Mv;
        }
        const float Di  = bpf(i36, Mv), Dj = bpf(j36, Mv);
        const float rsi = rsqf(Di),     rsj = rsqf(Dj);
        float Bv = Xv * (rsi * rsj);
        Bv = 0.5f * (Bv + bpf(tr4, Bv));                // symmetrize
        const float Lv = (i > j) ? Mv * rsj : ((i == j) ? Di * rsi : 0.0f);

        // ---- eigh(B) with T = L*V2 accumulated, diag in registers ----
        float D = bpf(j36, Bv);                         // col-replicated diag
        float T = Lv;
        #pragma unroll 1
        for (int sw = 0; sw < 4; ++sw) {
            jround<1>(Bv, T, D, lane, lane4, j36, tr4);
            jround<2>(Bv, T, D, lane, lane4, j36, tr4);
            jround<3>(Bv, T, D, lane, lane4, j36, tr4);
            jround<4>(Bv, T, D, lane, lane4, j36, tr4);
            jround<5>(Bv, T, D, lane, lane4, j36, tr4);
            jround<6>(Bv, T, D, lane, lane4, j36, tr4);
            jround<7>(Bv, T, D, lane, lane4, j36, tr4);
        }
        const float pw = exp2f_(wk * log2f_(fmaxf(D, EPSF)));  // lam^wk

        // ---- M' = T diag(pw) T^T via LDS rows (bitwise symmetric) ----
        myT[lane] = T;          // wave-private slot; intra-wave DS is in-order
        const float4 ti0 = *reinterpret_cast<const float4*>(myT + i8f);
        const float4 ti1 = *reinterpret_cast<const float4*>(myT + i8f + 4);
        const float4 tj0 = *reinterpret_cast<const float4*>(myT + j8f);
        const float4 tj1 = *reinterpret_cast<const float4*>(myT + j8f + 4);
        float Mn = rlf(pw, 0) * (ti0.x * tj0.x);
        Mn = fmaf(rlf(pw, 1), ti0.y * tj0.y, Mn);
        Mn = fmaf(rlf(pw, 2), ti0.z * tj0.z, Mn);
        Mn = fmaf(rlf(pw, 3), ti0.w * tj0.w, Mn);
        Mn = fmaf(rlf(pw, 4), ti1.x * tj1.x, Mn);
        Mn = fmaf(rlf(pw, 5), ti1.y * tj1.y, Mn);
        Mn = fmaf(rlf(pw, 6), ti1.z * tj1.z, Mn);
        Mn = fmaf(rlf(pw, 7), ti1.w * tj1.w, Mn);
        M = Mn;                                          // exactly symmetric
    }

    g_fm[(wid << 6) + lane] = M;
}

// ---------------- Phase 2: GL metric distances ----------------------------
// dist = sum_ij (ls_i rsig_i)(ls_j rsig_j) C_ij C_ji,  C = V^T (A V),
// with A = X^{-1} FM, eigh(A^T A) giving sigma^2 (D) and V.
__global__ void __launch_bounds__(256, 4)
dist_kernel(const float* __restrict__ x, float* __restrict__ out) {
    __shared__ __align__(16) float sAr[4][64];   // A row-major
    __shared__ __align__(16) float sAc[4][64];   // A col-major
    __shared__ __align__(16) float sVc[4][64];   // V col-major
    __shared__ __align__(16) float sTc[4][64];   // T1 = A*V col-major
    const int w = threadIdx.x >> 6;
    float* __restrict__ aRow = sAr[w];
    float* __restrict__ aCol = sAc[w];
    float* __restrict__ vCol = sVc[w];
    float* __restrict__ tCol = sTc[w];

    const int wid  = (blockIdx.x << 2) + w;                    // matrix id
    const int lane = threadIdx.x & 63;
    const int i = lane >> 3, j = lane & 7;
    const int lane4 = lane << 2;
    const int i32_ = i << 5, j4 = j << 2;
    const int j36 = j * 36;
    const int i8f = i << 3, j8f = j << 3;
    const int tr4 = ((j << 3) + i) << 2;
    const int chain = wid >> 8;                                // / SEQ

    float Xw = x[(size_t)wid * 64 + lane];
    float Yv = g_fm[(chain << 6) + lane];

    // A = X^{-1} FM via pivot-free Gauss-Jordan (X SPD, well-conditioned)
    #pragma unroll
    for (int k = 0; k < 8; ++k) {
        const float pr  = rcpf(rlf(Xw, k * 9));
        const float xk  = bpf((k << 5) + j4, Xw) * pr;
        const float yk  = bpf((k << 5) + j4, Yv) * pr;
        const float xik = bpf(i32_ + (k << 2), Xw);
        const bool  isk = (i == k);
        Xw = isk ? xk : fmaf(-xik, xk, Xw);
        Yv = isk ? yk : fmaf(-xik, yk, Yv);
    }
    const float Av = Yv;

    // stage A in LDS (row- and col-major); writes are 2-way aliased = free
    aRow[lane] = Av;
    aCol[j8f + i] = Av;

    // B = A^T A = colA_i . colA_j  (bitwise symmetric)
    float Bv = dot8(aCol + i8f, aCol + j8f);

    // eigh(B): sigma^2 in D, V = right singular vectors
    float V = (i == j) ? 1.0f : 0.0f;
    float D = bpf(j36, Bv);
    #pragma unroll 1
    for (int sw = 0; sw < 4; ++sw) {
        jround<1>(Bv, V, D, lane, lane4, j36, tr4);
        jround<2>(Bv, V, D, lane, lane4, j36, tr4);
        jround<3>(Bv, V, D, lane, lane4, j36, tr4);
        jround<4>(Bv, V, D, lane, lane4, j36, tr4);
        jround<5>(Bv, V, D, lane, lane4, j36, tr4);
        jround<6>(Bv, V, D, lane, lane4, j36, tr4);
        jround<7>(Bv, V, D, lane, lane4, j36, tr4);
    }
    const float sig2 = fmaxf(D, 1e-20f);
    const float g = (0.34657359028f * log2f_(sig2)) * rsqf(sig2); // ls_j*rsig_j

    // T1 = A V  (rowA_i . colV_j)
    vCol[j8f + i] = V;
    const float T1 = dot8(aRow + i8f, vCol + j8f);

    // C = V^T T1  (colV_i . colT1_j)
    tCol[j8f + i] = T1;
    const float C = dot8(vCol + i8f, tCol + j8f);

    const float Ct = bpf(tr4, C);
    const float gi = bpf(tr4, g);

    float contrib = gi * g * C * Ct;
    #pragma unroll
    for (int off = 32; off; off >>= 1)
        contrib += __shfl_xor(contrib, off, 64);

    if (lane == 0) out[wid] = contrib;
}

extern "C" void kernel_launch(void* const* d_in, const int* in_sizes, int n_in,
                              void* d_out, int out_size, void* d_ws, size_t ws_size,
                              hipStream_t stream) {
    const float* x = (const float*)d_in[0];
    float* out = (float*)d_out;
    (void)in_sizes; (void)n_in; (void)d_ws; (void)ws_size; (void)out_size;

    // Phase 1: 2048 chains, 1 wave each, 4 waves/block
    hipLaunchKernelGGL(fm_kernel, dim3(NCHAIN / 4), dim3(256), 0, stream, x);
    // Phase 2: 524288 matrices, 1 wave each
    hipLaunchKernelGGL(dist_kernel, dim3(NMAT / 4), dim3(256), 0, stream, x, out);
}

// Round 7
// 2116.055 us; speedup vs baseline: 4.8022x; 1.0544x over previous
//
#include <hip/hip_runtime.h>
#include <stdint.h>

// Problem constants (B=32, C1=64, C2=16, C3=16, N=8)
#define EPSF    1e-10f
#define NCHAIN  2048        // B*C1
#define SEQ     256         // C2*C3
#define NMAT    (NCHAIN*SEQ)

// Fréchet means live here between the two kernels (512 KB, fully
// rewritten by fm_kernel on every call -> deterministic).
__device__ float g_fm[NCHAIN * 64];

__device__ __forceinline__ float rcpf(float x) { return __builtin_amdgcn_rcpf(x); }
__device__ __forceinline__ float rsqf(float x) { return __builtin_amdgcn_rsqf(x); }
__device__ __forceinline__ float exp2f_(float x) { return __builtin_amdgcn_exp2f(x); }
__device__ __forceinline__ float log2f_(float x) { return __builtin_amdgcn_logf(x); }

// bpermute with pre-shifted (byte) address
__device__ __forceinline__ float bpf(int addr4, float v) {
    return __int_as_float(__builtin_amdgcn_ds_bpermute(addr4, __float_as_int(v)));
}
// uniform-lane broadcast (diagonal pivots)
__device__ __forceinline__ float rlf(float v, int srcLane) {
    return __int_as_float(__builtin_amdgcn_readlane(__float_as_int(v), srcLane));
}
// lane-XOR shuffle via ds_swizzle immediate (DS pipe), mask < 32
template<int MASK>
__device__ __forceinline__ float sxf(float v) {
    static_assert(MASK > 0 && MASK < 32, "swizzle mask");
    return __int_as_float(__builtin_amdgcn_ds_swizzle(
        __float_as_int(v), (MASK << 10) | 0x1F));
}
// DPP mov: cross-lane on the VALU pipe, zero DS cost.
// 0xB1=quad_perm xor1, 0x4E=xor2, 0x1B=xor3, 0x141=row_half_mirror (xor7),
// 0x128=row_ror:8 (xor8 within 16), 0x111/0x112/0x114/0x118=row_shr 1/2/4/8,
// 0x142=bcast15, 0x143=bcast31.
template<int CTRL, int RMASK = 0xF, bool BC = true>
__device__ __forceinline__ float dppf(float v) {
    return __int_as_float(__builtin_amdgcn_update_dpp(
        0, __float_as_int(v), CTRL, RMASK, 0xF, BC));
}
// lane XOR M (M=1..7) entirely via DPP (1-2 VALU ops, zero DS)
template<int M>
__device__ __forceinline__ float cxf(float v) {
    if constexpr      (M == 1) return dppf<0xB1>(v);
    else if constexpr (M == 2) return dppf<0x4E>(v);
    else if constexpr (M == 3) return dppf<0x1B>(v);
    else if constexpr (M == 4) return dppf<0x141>(dppf<0x1B>(v));  // 7^3
    else if constexpr (M == 5) return dppf<0x141>(dppf<0x4E>(v));  // 7^2
    else if constexpr (M == 6) return dppf<0x141>(dppf<0xB1>(v));  // 7^1
    else                       return dppf<0x141>(v);              // 7
}

// wave64 sum -> returned on all lanes' lane-63 slot (read via lane 63 store)
__device__ __forceinline__ float wave_sum63(float v) {
    v += dppf<0x111>(v);                    // += lane-1   (row_shr:1)
    v += dppf<0x112>(v);                    // += lane-2
    v += dppf<0x114>(v);                    // += lane-4
    v += dppf<0x118>(v);                    // += lane-8   -> lane15/31/47/63
    v += dppf<0x142, 0xA, false>(v);        // bcast15 into rows 1,3
    v += dppf<0x143, 0xC, false>(v);        // bcast31 into rows 2,3
    return v;                               // lane 63 holds the total
}

// 8-float dot from two LDS rows (4x ds_read_b128, 2-way bank alias = free)
__device__ __forceinline__ float dot8(const float* __restrict__ a,
                                      const float* __restrict__ b) {
    const float4 a0 = *reinterpret_cast<const float4*>(a);
    const float4 a1 = *reinterpret_cast<const float4*>(a + 4);
    const float4 b0 = *reinterpret_cast<const float4*>(b);
    const float4 b1 = *reinterpret_cast<const float4*>(b + 4);
    float s = a0.x * b0.x;
    s = fmaf(a0.y, b0.y, s); s = fmaf(a0.z, b0.z, s); s = fmaf(a0.w, b0.w, s);
    s = fmaf(a1.x, b1.x, s); s = fmaf(a1.y, b1.y, s); s = fmaf(a1.z, b1.z, s);
    s = fmaf(a1.w, b1.w, s);
    return s;
}

// Jacobi rotation params for pair {j, j^m}. dj = own diag, dm = partner
// diag, apq = pair off-diagonal, sg = tie-break sign (+1 for pair-second).
__device__ __forceinline__ void jrot2(float dj, float dm, float apq, float sg,
                                      float &c, float &bs) {
    const float dd = dj - dm;
    const float h  = apq + apq;
    const float r2 = fmaf(dd, dd, fmaf(h, h, 1e-36f));
    const float rr = rsqf(r2);                          // 1/r
    const float c2 = fmaf(0.5f * fabsf(dd), rr, 0.5f);  // cos^2 = (1+|d|/r)/2
    const float ic = rsqf(c2);                          // 1/c
    const float chi = (dd != 0.0f) ? copysignf(1.0f, dd) : sg;
    const bool  tiny = r2 < 1e-33f;
    c  = tiny ? 1.0f : c2 * ic;                         // sqrt(c2)
    bs = tiny ? 0.0f : apq * chi * rr * ic;             // s*sign
}

// ---- unified Jacobi round, DPP-assisted: 3-4 DS ops (was 7) -------------
// A: active symmetric matrix; W: accumulates W <- W*J (V or L*V);
// D: column-replicated diagonal of A, maintained in-register.
template<int M>
__device__ __forceinline__ void jround(float &A, float &W, float &D,
                                       const int lane, const int lane4,
                                       const int j36, const int tr4) {
    constexpr int HB = (M & 4) ? 4 : ((M & 2) ? 2 : 1);
    const float dmj = cxf<M>(D);                // DPP (was DS)
    const float aqj = bpf(j36 ^ (M << 2), A);   // A[j, j^M] gather: DS
    const float sgj = (lane & HB) ? 1.0f : -1.0f;
    float aj, bj;
    jrot2(D, dmj, aqj, sgj, aj, bj);
    const float ai = bpf(tr4, aj);              // row params = transpose: DS
    const float bi = bpf(tr4, bj);              // DS
    const float Ac = cxf<M>(A);                 // A[i, j^M]: DPP
    A = fmaf(bj, Ac, aj * A);                   // A <- A J
    float Ar;                                   // A[i^M, j] (post col-update)
    if constexpr (M == 1)            Ar = dppf<0x128>(A);      // xor8: DPP
    else if constexpr ((M << 3) < 32) Ar = sxf<(M << 3)>(A);   // xor16/24: DS
    else                              Ar = bpf(lane4 ^ (M << 5), A);  // DS
    A = fmaf(bi, Ar, ai * A);                   // A <- J^T A
    const float Wc = cxf<M>(W);                 // DPP
    W = fmaf(bj, Wc, aj * W);
    const float d0 = fmaf(bj, aqj, aj * D);     // pair-subspace diag update
    const float d1 = fmaf(bj, dmj, aj * aqj);
    D = fmaf(bj, d1, aj * d0);
}

// ---------------- Phase 1: recursive Frechet mean (sequential scan) -------
// Geodesic step, factor-invariant form with fused two-sided elimination:
//   LDL^T Gauss elimination on M while applying the SAME eliminations
//   two-sided to X:  after 8 steps  X -> L_u^{-1} X L_u^{-T},  diag(M) -> D.
//   B = L^{-1} X L^{-T},  L = L_u D^{1/2}.  M' = T diag(lam^w) T^T with
//   T = L*V2 accumulated inside the Jacobi loop; final matmul via LDS rows.
__global__ void __launch_bounds__(256, 2)
fm_kernel(const float* __restrict__ x) {
    __shared__ __align__(16) float sT[4][64];
    float* __restrict__ myT = sT[threadIdx.x >> 6];

    const int wid  = (blockIdx.x << 2) + (threadIdx.x >> 6);   // chain id
    const int lane = threadIdx.x & 63;
    const int i = lane >> 3, j = lane & 7;
    const int lane4 = lane << 2;
    const int i32_ = i << 5, j4 = j << 2;
    const int i36 = i * 36, j36 = j * 36;
    const int i8f = i << 3, j8f = j << 3;
    const int tr4 = ((j << 3) + i) << 2;

    const float* __restrict__ base = x + (size_t)wid * (SEQ * 64);
    float M = base[lane];                      // M_1 = X_1

    #pragma unroll 1
    for (int k = 1; k < SEQ; ++k) {
        const float Xk = base[(k << 6) + lane];
        const float wk = rcpf((float)(k + 1));

        // ---- fused LDL^T elimination + two-sided solve (8 x 1-bp depth) --
        float Mv = M, Xv = Xk;
        #pragma unroll
        for (int kk = 0; kk < 8; ++kk) {
            const float piv = rlf(Mv, kk * 9);          // uniform: readlane
            const float Xkk = rlf(Xv, kk * 9);
            const float rp  = rcpf(piv);
            const float Mik = bpf(i32_ + (kk << 2), Mv);
            const float Mkj = bpf((kk << 5) + j4,   Mv);
            const float Xkj = bpf((kk << 5) + j4,   Xv);
            const float Xik = bpf(i32_ + (kk << 2), Xv);
            const float mi = (i > kk) ? Mik * rp : 0.0f;
            const float mj = (j > kk) ? Mkj * rp : 0.0f;
            Xv = fmaf(mi * mj, Xkk, fmaf(-mj, Xik, fmaf(-mi, Xkj, Xv)));
            Mv = ((i > kk) && (j > kk)) ? fmaf(-mi, Mkj, Mv) : Mv;
        }
        const float Di  = bpf(i36, Mv), Dj = bpf(j36, Mv);
        const float rsi = rsqf(Di),     rsj = rsqf(Dj);
        float Bv = Xv * (rsi * rsj);
        Bv = 0.5f * (Bv + bpf(tr4, Bv));                // symmetrize
        const float Lv = (i > j) ? Mv * rsj : ((i == j) ? Di * rsi : 0.0f);

        // ---- eigh(B) with T = L*V2 accumulated, diag in registers ----
        float D = bpf(j36, Bv);                         // col-replicated diag
        float T = Lv;
        #pragma unroll 1
        for (int sw = 0; sw < 4; ++sw) {
            jround<1>(Bv, T, D, lane, lane4, j36, tr4);
            jround<2>(Bv, T, D, lane, lane4, j36, tr4);
            jround<3>(Bv, T, D, lane, lane4, j36, tr4);
            jround<4>(Bv, T, D, lane, lane4, j36, tr4);
            jround<5>(Bv, T, D, lane, lane4, j36, tr4);
            jround<6>(Bv, T, D, lane, lane4, j36, tr4);
            jround<7>(Bv, T, D, lane, lane4, j36, tr4);
        }
        const float pw = exp2f_(wk * log2f_(fmaxf(D, EPSF)));  // lam^wk

        // ---- M' = T diag(pw) T^T via LDS rows (bitwise symmetric) ----
        myT[lane] = T;          // wave-private slot; intra-wave DS is in-order
        const float4 ti0 = *reinterpret_cast<const float4*>(myT + i8f);
        const float4 ti1 = *reinterpret_cast<const float4*>(myT + i8f + 4);
        const float4 tj0 = *reinterpret_cast<const float4*>(myT + j8f);
        const float4 tj1 = *reinterpret_cast<const float4*>(myT + j8f + 4);
        float Mn = rlf(pw, 0) * (ti0.x * tj0.x);
        Mn = fmaf(rlf(pw, 1), ti0.y * tj0.y, Mn);
        Mn = fmaf(rlf(pw, 2), ti0.z * tj0.z, Mn);
        Mn = fmaf(rlf(pw, 3), ti0.w * tj0.w, Mn);
        Mn = fmaf(rlf(pw, 4), ti1.x * tj1.x, Mn);
        Mn = fmaf(rlf(pw, 5), ti1.y * tj1.y, Mn);
        Mn = fmaf(rlf(pw, 6), ti1.z * tj1.z, Mn);
        Mn = fmaf(rlf(pw, 7), ti1.w * tj1.w, Mn);
        M = Mn;                                          // exactly symmetric
    }

    g_fm[(wid << 6) + lane] = M;
}

// ---------------- Phase 2: GL metric distances ----------------------------
// dist = sum_ij (ls_i rsig_i)(ls_j rsig_j) C_ij C_ji,  C = V^T (A V),
// with A = X^{-1} FM, eigh(A^T A) giving sigma^2 (D) and V.
__global__ void __launch_bounds__(256, 4)
dist_kernel(const float* __restrict__ x, float* __restrict__ out) {
    __shared__ __align__(16) float sAr[4][64];   // A row-major
    __shared__ __align__(16) float sAc[4][64];   // A col-major
    __shared__ __align__(16) float sVc[4][64];   // V col-major
    __shared__ __align__(16) float sTc[4][64];   // T1 = A*V col-major
    const int w = threadIdx.x >> 6;
    float* __restrict__ aRow = sAr[w];
    float* __restrict__ aCol = sAc[w];
    float* __restrict__ vCol = sVc[w];
    float* __restrict__ tCol = sTc[w];

    const int wid  = (blockIdx.x << 2) + w;                    // matrix id
    const int lane = threadIdx.x & 63;
    const int i = lane >> 3, j = lane & 7;
    const int lane4 = lane << 2;
    const int i32_ = i << 5, j4 = j << 2;
    const int j36 = j * 36;
    const int i8f = i << 3, j8f = j << 3;
    const int tr4 = ((j << 3) + i) << 2;
    const int chain = wid >> 8;                                // / SEQ

    float Xw = x[(size_t)wid * 64 + lane];
    float Yv = g_fm[(chain << 6) + lane];

    // A = X^{-1} FM via pivot-free Gauss-Jordan (X SPD, well-conditioned)
    #pragma unroll
    for (int k = 0; k < 8; ++k) {
        const float pr  = rcpf(rlf(Xw, k * 9));
        const float xk  = bpf((k << 5) + j4, Xw) * pr;
        const float yk  = bpf((k << 5) + j4, Yv) * pr;
        const float xik = bpf(i32_ + (k << 2), Xw);
        const bool  isk = (i == k);
        Xw = isk ? xk : fmaf(-xik, xk, Xw);
        Yv = isk ? yk : fmaf(-xik, yk, Yv);
    }
    const float Av = Yv;

    // stage A in LDS (row- and col-major)
    aRow[lane] = Av;
    aCol[j8f + i] = Av;

    // B = A^T A = colA_i . colA_j  (bitwise symmetric)
    float Bv = dot8(aCol + i8f, aCol + j8f);

    // eigh(B): sigma^2 in D, V = right singular vectors
    float V = (i == j) ? 1.0f : 0.0f;
    float D = bpf(j36, Bv);
    #pragma unroll 1
    for (int sw = 0; sw < 4; ++sw) {
        jround<1>(Bv, V, D, lane, lane4, j36, tr4);
        jround<2>(Bv, V, D, lane, lane4, j36, tr4);
        jround<3>(Bv, V, D, lane, lane4, j36, tr4);
        jround<4>(Bv, V, D, lane, lane4, j36, tr4);
        jround<5>(Bv, V, D, lane, lane4, j36, tr4);
        jround<6>(Bv, V, D, lane, lane4, j36, tr4);
        jround<7>(Bv, V, D, lane, lane4, j36, tr4);
    }
    const float sig2 = fmaxf(D, 1e-20f);
    const float g = (0.34657359028f * log2f_(sig2)) * rsqf(sig2); // ls_j*rsig_j

    // T1 = A V  (rowA_i . colV_j)
    vCol[j8f + i] = V;
    const float T1 = dot8(aRow + i8f, vCol + j8f);

    // C = V^T T1  (colV_i . colT1_j)
    tCol[j8f + i] = T1;
    const float C = dot8(vCol + i8f, tCol + j8f);

    const float Ct = bpf(tr4, C);
    const float gi = bpf(tr4, g);

    const float total = wave_sum63(gi * g * C * Ct);   // DPP reduce, 0 DS
    if (lane == 63) out[wid] = total;

    (void)aRow;
}

extern "C" void kernel_launch(void* const* d_in, const int* in_sizes, int n_in,
                              void* d_out, int out_size, void* d_ws, size_t ws_size,
                              hipStream_t stream) {
    const float* x = (const float*)d_in[0];
    float* out = (float*)d_out;
    (void)in_sizes; (void)n_in; (void)d_ws; (void)ws_size; (void)out_size;

    // Phase 1: 2048 chains, 1 wave each, 4 waves/block
    hipLaunchKernelGGL(fm_kernel, dim3(NCHAIN / 4), dim3(256), 0, stream, x);
    // Phase 2: 524288 matrices, 1 wave each
    hipLaunchKernelGGL(dist_kernel, dim3(NMAT / 4), dim3(256), 0, stream, x, out);
}